// Round 13
// baseline (201.375 us; speedup 1.0000x reference)
//
#include <hip/hip_runtime.h>
#include <hip/hip_bf16.h>

// ---------------- constants ----------------
#define NN   2708      // nodes
#define INS  1433      // input features
#define MM   8         // mechanisms
#define NP   2720      // N padded to mult of 32 (j / n dimension)
#define WPR  85        // NP/32 words per adjacency row (bit-packed)
#define KP   1440      // INS padded to mult of 32
#define NKC  45        // KP/32 k-chunks
#define RP   2752      // rows padded to mult of 64 for GEMM
#define C9   576       // 9*64 columns of big GEMM (8 mechs + conditioner hidden)
#define OC   512       // M*OUTS output columns

// canon small-tensor layout (floats): a_src[512] a_dst[512] bc1[64] bc2[16] Wc2[1024]
#define CAN_ASRC 0
#define CAN_ADST 512
#define CAN_BC1  1024
#define CAN_BC2  1088
#define CAN_WC2  1104
#define CAN_TOT  2128

// fused pack kernel block ranges: [adj | x | wt | canon]
#define ADJ_WAVES (NN * 11)               // one wave per (row, 256-j chunk)
#define ADJBLK ((ADJ_WAVES + 3) / 4)      // 7447
#define XBLK   1935                        // RP*KP/2048 (8 elems/thread)
#define WTBLK  (9 * 23)                    // 207
#define PACK_TOT (ADJBLK + XBLK + WTBLK + 1)

typedef unsigned short u16;
typedef unsigned int   u32;
typedef __attribute__((ext_vector_type(8))) short bf16x8;
typedef __attribute__((ext_vector_type(4))) float f32x4;

static __device__ __forceinline__ u16 f2bfu(float f) {
    union { float f; u32 u; } v; v.f = f;
    u32 u = v.u;
    u32 r = (u + 0x7fffu + ((u >> 16) & 1u)) >> 16;   // RNE
    return (u16)r;
}
static __device__ __forceinline__ float bfu2f(u16 b) {
    union { u32 u; float f; } v; v.u = ((u32)b) << 16;
    return v.f;
}
// packed RNE f32x2 -> bf16x2 (v_cvt_pk_bf16_f32 on gfx950)
static __device__ __forceinline__ u32 pk_bf16(float a, float b) {
    union { __hip_bfloat162 h; u32 w; } p;
    p.h = __float22bfloat162_rn(make_float2(a, b));
    return p.w;
}
// ordered-uint key for float atomicMax (finite values)
static __device__ __forceinline__ u32 fkey(float f) {
    u32 u = __float_as_uint(f);
    return (u & 0x80000000u) ? ~u : (u | 0x80000000u);
}
static __device__ __forceinline__ float funkey(u32 k) {
    u32 u = (k & 0x80000000u) ? (k & 0x7fffffffu) : ~k;
    return __uint_as_float(u);
}

// ctr[0..31] = per-block x denormal counts; ctr[32..63] = per-block adj flag bits
// bits: 1=gt1, 2=bf16, 4=f32, 8=f16, 16=odd-nonzero
static __device__ __forceinline__ int aflag_decode(int b) {
    if (b & 2)  return 3;   // bf16
    if (b & 4)  return 4;   // f32
    if (b & 8)  return 5;   // f16
    if (b & 1)  return 1;   // uint8
    if (b & 16) return 0;   // int32
    return 2;               // int64
}

// ---------------- probes: no atomics, per-block result words ----------------
__global__ void k_probe(const u32* __restrict__ x_raw, const u32* __restrict__ adj_raw,
                        int* __restrict__ ctr) {
    const int b = blockIdx.x, t = threadIdx.x;
    __shared__ int sred[4];
    if (b < 32) {
        int local = 0;
        #pragma unroll
        for (int k = 0; k < 8; ++k) {
            u32 v = x_raw[b * 2048 + k * 256 + t];
            u32 lo = v & 0xffffu, hi = v >> 16;
            if ((lo & 0x7f80u) == 0u && lo != 0u) local++;   // fp32 mantissa pattern
            if ((hi & 0x7f80u) == 0u && hi != 0u) local++;
        }
        #pragma unroll
        for (int off = 32; off > 0; off >>= 1) local += __shfl_xor(local, off, 64);
        if ((t & 63) == 0) sred[t >> 6] = local;
        __syncthreads();
        if (t == 0) ctr[b] = sred[0] + sred[1] + sred[2] + sred[3];
    } else {
        int fl = 0;
        #pragma unroll
        for (int k = 0; k < 8; ++k) {
            int w = (b - 32) * 2048 + k * 256 + t;
            u32 v = adj_raw[w];
            if (v > 1u)           fl |= 1;
            if (v == 0x3f803f80u) fl |= 2;
            if (v == 0x3f800000u) fl |= 4;
            if (v == 0x3c003c00u) fl |= 8;
            if ((w & 1) && v)     fl |= 16;
        }
        #pragma unroll
        for (int off = 32; off > 0; off >>= 1) fl |= __shfl_xor(fl, off, 64);
        if ((t & 63) == 0) sred[t >> 6] = fl;
        __syncthreads();
        if (t == 0) ctr[b] = sred[0] | sred[1] | sred[2] | sred[3];
    }
}

static __device__ __forceinline__ u16 load_as_bf16(const void* p, size_t idx, int fp32) {
    if (fp32) return f2bfu(((const float*)p)[idx]);
    return ((const u16*)p)[idx];
}
static __device__ __forceinline__ float load_as_f32(const void* p, size_t idx, int fp32) {
    if (fp32) return ((const float*)p)[idx];
    return bfu2f(((const u16*)p)[idx]);
}

// ---------------- fused pack: adj-bitpack | x fragment tiles | W transpose | canon ----------------
__global__ void k_pack(const void* __restrict__ x, const void* __restrict__ adj,
                       const void* __restrict__ W, const void* __restrict__ Wc1,
                       const void* a_src, const void* a_dst, const void* bc1,
                       const void* bc2, const void* Wc2,
                       u16* __restrict__ xpf, u16* __restrict__ WTf,
                       u32* __restrict__ adjT, float* __restrict__ canon,
                       u32* __restrict__ maxdKey, const int* __restrict__ ctr) {
    __shared__ float lds[64][65];
    __shared__ int sflags[2];
    const int t = threadIdx.x;
    if (t < 64) {
        int v = ctr[t];
        int cnt  = (t < 32) ? v : 0;
        int bits = (t >= 32) ? v : 0;
        #pragma unroll
        for (int off = 32; off > 0; off >>= 1) {
            cnt  += __shfl_xor(cnt, off, 64);
            bits |= __shfl_xor(bits, off, 64);
        }
        if (t == 0) { sflags[0] = cnt; sflags[1] = bits; }
    }
    __syncthreads();
    const int fp32 = sflags[0] > 32;

    const int bid = blockIdx.x;
    if (bid < ADJBLK) {
        const int f = aflag_decode(sflags[1]);
        const int wid  = bid * 4 + (t >> 6);
        const int lane = t & 63;
        const int i = wid / 11;
        const int c256 = wid - i * 11;
        if (i >= NN) return;
        const int jb0 = c256 * 256;
        #pragma unroll
        for (int s = 0; s < 4; ++s) {
            const int jb = jb0 + s * 64;
            if (jb >= NP) break;
            const int j = jb + lane;
            int v = 0;
            if (j < NN) {
                size_t idx = (size_t)i * NN + j;
                if      (f == 0) v = ((const int*)adj)[idx] != 0;
                else if (f == 1) v = ((const unsigned char*)adj)[idx] != 0;
                else if (f == 2) v = ((const long long*)adj)[idx] != 0;
                else if (f == 4) v = ((const float*)adj)[idx] != 0.f;
                else             v = ((const u16*)adj)[idx] != 0;
            }
            unsigned long long mask = __ballot(v);
            if (lane == 0) {
                const int ww = jb >> 5;
                adjT[(size_t)ww * NP + i] = (u32)mask;
                if (ww + 1 < WPR) adjT[(size_t)(ww + 1) * NP + i] = (u32)(mask >> 32);
            }
        }
    } else if (bid < ADJBLK + XBLK) {
        const int base = (bid - ADJBLK) * 2048 + t;
        #pragma unroll
        for (int s = 0; s < 8; ++s) {
            const int e = base + s * 256;
            const int t1 = e >> 9, sub = e & 511;
            const int r = sub >> 5, kloc = sub & 31;
            const int it = t1 / NKC, kc = t1 - it * NKC;
            const int row = it * 16 + r, col = kc * 32 + kloc;
            u16 v = 0;
            if (row < NN && col < INS) v = load_as_bf16(x, (size_t)row * INS + col, fp32);
            xpf[e] = v;
        }
    } else if (bid < ADJBLK + XBLK + WTBLK) {
        const int b2 = bid - ADJBLK - XBLK;
        const int mblk = b2 / 23, ktile = b2 - mblk * 23;
        #pragma unroll
        for (int ii = 0; ii < 16; ++ii) {
            int l = t * 16 + ii;
            int k_in = l >> 6, o = l & 63;
            int k = ktile * 64 + k_in;
            float v = 0.f;
            if (k < INS) {
                if (mblk < 8) v = load_as_f32(W, ((size_t)mblk * INS + k) * 64 + o, fp32);
                else          v = load_as_f32(Wc1, (size_t)k * 64 + o, fp32);
            }
            lds[k_in][o] = v;
        }
        __syncthreads();
        #pragma unroll
        for (int ii = 0; ii < 16; ++ii) {
            int e2 = t * 16 + ii;
            int ct2 = e2 >> 10, kc2 = (e2 >> 9) & 1;
            int r = (e2 >> 5) & 15, kloc = e2 & 31;
            int kc = ktile * 2 + kc2;
            if (kc < NKC) {
                int ct = mblk * 4 + ct2;
                WTf[(((size_t)ct * NKC + kc) * 16 + r) * 32 + kloc] =
                    f2bfu(lds[kc2 * 32 + kloc][ct2 * 16 + r]);
            }
        }
    } else {
        if (t < 8) maxdKey[t] = 0u;    // identity for ordered-uint max over finite floats
        for (int e = t; e < CAN_TOT; e += 256) {
            float v;
            if      (e < CAN_ADST) v = load_as_f32(a_src, e - CAN_ASRC, fp32);
            else if (e < CAN_BC1)  v = load_as_f32(a_dst, e - CAN_ADST, fp32);
            else if (e < CAN_BC2)  v = load_as_f32(bc1,  e - CAN_BC1, fp32);
            else if (e < CAN_WC2)  v = load_as_f32(bc2,  e - CAN_BC2, fp32);
            else                   v = load_as_f32(Wc2,  e - CAN_WC2, fp32);
            canon[e] = v;
        }
    }
}

// ---------------- big GEMM: 2 row-tiles x 2 col-tiles per wave, 1548 waves ----------------
__launch_bounds__(64)
__global__ void k_gemm(const u16* __restrict__ xpf, const u16* __restrict__ WTf,
                       float* __restrict__ h_pre) {
    const int lane = threadIdx.x;
    const int r    = lane & 15;
    const int quad = lane >> 4;
    const int it0  = blockIdx.x * 2;          // two 16-row i-tiles (0..171)
    const int ct0  = blockIdx.y * 2;          // two 16-col c-tiles (0..35)

    const u16* aP0 = xpf + (size_t)it0 * NKC * 512 + r * 32 + quad * 8;
    const u16* aP1 = aP0 + (size_t)NKC * 512;
    const u16* bP0 = WTf + (size_t)ct0 * NKC * 512 + r * 32 + quad * 8;
    const u16* bP1 = bP0 + (size_t)NKC * 512;

    f32x4 acc[2][2];
    #pragma unroll
    for (int a = 0; a < 2; ++a)
        #pragma unroll
        for (int b = 0; b < 2; ++b) acc[a][b] = (f32x4){0.f, 0.f, 0.f, 0.f};

    #pragma unroll 3
    for (int kc = 0; kc < NKC; ++kc) {
        bf16x8 a0 = *(const bf16x8*)(aP0 + kc * 512);
        bf16x8 a1 = *(const bf16x8*)(aP1 + kc * 512);
        bf16x8 b0 = *(const bf16x8*)(bP0 + kc * 512);
        bf16x8 b1 = *(const bf16x8*)(bP1 + kc * 512);
        acc[0][0] = __builtin_amdgcn_mfma_f32_16x16x32_bf16(a0, b0, acc[0][0], 0, 0, 0);
        acc[0][1] = __builtin_amdgcn_mfma_f32_16x16x32_bf16(a0, b1, acc[0][1], 0, 0, 0);
        acc[1][0] = __builtin_amdgcn_mfma_f32_16x16x32_bf16(a1, b0, acc[1][0], 0, 0, 0);
        acc[1][1] = __builtin_amdgcn_mfma_f32_16x16x32_bf16(a1, b1, acc[1][1], 0, 0, 0);
    }

    #pragma unroll
    for (int a = 0; a < 2; ++a) {
        #pragma unroll
        for (int reg = 0; reg < 4; ++reg) {
            const int ii = (it0 + a) * 16 + quad * 4 + reg;
            if (ii < NN) {
                float* orow = h_pre + (size_t)ii * C9 + ct0 * 16;
                orow[ 0 + r] = acc[a][0][reg];
                orow[16 + r] = acc[a][1][reg];
            }
        }
    }
}

// ---------------- FiLM + inline conditioner + scores + HT tiles + maxd atomicMax ----------------
__launch_bounds__(256)
__global__ void k_film(const float* __restrict__ h_pre, const float* __restrict__ canon,
                       u16* __restrict__ HTf, float* __restrict__ e_srcP,
                       float* __restrict__ e_dstP, u32* __restrict__ maxdKey) {
    const int m  = blockIdx.y;
    const int n0 = blockIdx.x * 32;
    const int t  = threadIdx.x, wave = t >> 6, o = t & 63;
    __shared__ float hbuf[32][66];   // fp32; +2 pad
    __shared__ float smx[4];

    const float wg = canon[CAN_WC2 + o * 16 + m];
    const float wb = canon[CAN_WC2 + o * 16 + m + 8];
    const float as = canon[CAN_ASRC + m * 64 + o];
    const float ad = canon[CAN_ADST + m * 64 + o];
    const float b1 = canon[CAN_BC1 + o];
    const float g0 = canon[CAN_BC2 + m], b0 = canon[CAN_BC2 + m + 8];

    float mxd = -3.0e38f;
    #pragma unroll
    for (int it = 0; it < 8; ++it) {
        const int nl = wave * 8 + it, n = n0 + nl;
        const bool valid = n < NN;
        float hv = 0.f;
        if (valid) hv = h_pre[(size_t)n * C9 + 512 + o] + b1;   // coalesced 256 B row
        hv = hv > 0.f ? hv : 0.f;
        float pg = hv * wg, pb = hv * wb;
        #pragma unroll
        for (int off = 32; off > 0; off >>= 1) {
            pg += __shfl_xor(pg, off, 64);
            pb += __shfl_xor(pb, off, 64);
        }
        const float g = pg + g0, bb = pb + b0;
        float h = 0.f;
        if (valid) h = g * h_pre[(size_t)n * C9 + m * 64 + o] + bb;  // coalesced
        float ps = h * as, pd = h * ad;
        #pragma unroll
        for (int off = 32; off > 0; off >>= 1) {
            ps += __shfl_xor(ps, off, 64);
            pd += __shfl_xor(pd, off, 64);
        }
        if (o == 0) { e_srcP[m * NP + n] = ps; e_dstP[m * NP + n] = pd; }
        mxd = fmaxf(mxd, pd);                 // pd identical on all lanes after butterfly
        hbuf[nl][o] = h;
    }
    if (o == 0) smx[wave] = mxd;
    __syncthreads();
    if (t == 0) {
        const float bm = fmaxf(fmaxf(smx[0], smx[1]), fmaxf(smx[2], smx[3]));
        atomicMax(&maxdKey[m], fkey(bm));
    }
    // write one fragment-major HT tile (o-major, 32-j inner), fully coalesced
    u32* ht32 = (u32*)(HTf + ((size_t)m * WPR + (n0 >> 5)) * 2048);
    #pragma unroll
    for (int rep = 0; rep < 4; ++rep) {
        const int idx = rep * 256 + t;
        const int oo = idx >> 4, jp = idx & 15;
        ht32[idx] = pk_bf16(hbuf[2 * jp][oo], hbuf[2 * jp + 1][oo]);
    }
}

// ---------------- attention + PV: E/F in staging, double-buffered HT prefetch ----------------
__launch_bounds__(256)
__global__ void k_attn(const u32* __restrict__ adjT, const float* __restrict__ e_srcP,
                       const float* __restrict__ e_dstP, const u32* __restrict__ maxdKey,
                       const u16* __restrict__ HTf, void* __restrict__ outv,
                       const int* __restrict__ ctr) {
    const int m = blockIdx.y, i0 = blockIdx.x * 16;
    const int t = threadIdx.x;
    const int wave = t >> 6, lane = t & 63;
    const int r = lane & 15, quad = lane >> 4;
    const int i = min(i0 + r, NN - 1);

    __shared__ float sE[2 * NP];      // E1 | E2; reused as reduction buffer after loop
    __shared__ u32 sAdj[WPR * 16];    // [tile][r]
    __shared__ int sflag;

    const u16* hbase = HTf + (size_t)m * WPR * 2048 + r * 32 + quad * 8;

    // issue first HT tile's loads BEFORE the staging barrier (overlap latency)
    bf16x8 cur[4];
    {
        const u16* ht0 = hbase + (size_t)wave * 2048;
        #pragma unroll
        for (int nt = 0; nt < 4; ++nt) cur[nt] = *(const bf16x8*)(ht0 + nt * 512);
    }

    const float maxd = funkey(maxdKey[m]);
    if (t == 0) {
        int s = 0;
        #pragma unroll
        for (int k = 0; k < 32; ++k) s += ctr[k];
        sflag = s > 32;
    }
    for (int idx = t; idx < NP; idx += 256) {
        const float d = e_dstP[m * NP + idx] - maxd;
        sE[idx]      = __expf(d);
        sE[NP + idx] = __expf(0.2f * d);
    }
    for (int w = t; w < WPR * 16; w += 256) {
        const int tile = w >> 4, rr = w & 15;
        sAdj[w] = adjT[(size_t)tile * NP + min(i0 + rr, NN - 1)];
    }
    __syncthreads();

    const float v0 = e_srcP[m * NP + i] + maxd;
    const float rmax = v0 > 0.f ? v0 : 0.2f * v0;
    const float F1 = __expf(v0 - rmax);
    const float F2 = __expf(0.2f * v0 - rmax);

    f32x4 acc[4], accl;
    #pragma unroll
    for (int nt = 0; nt < 4; ++nt) acc[nt] = (f32x4){0.f, 0.f, 0.f, 0.f};
    accl = (f32x4){0.f, 0.f, 0.f, 0.f};

    bf16x8 ones;
    #pragma unroll
    for (int kk = 0; kk < 8; ++kk) ones[kk] = (short)0x3f80;

    // waves round-robin over j-chunks; double-buffered HT prefetch hides HBM latency
    for (int jc = wave * 32; jc < NP; jc += 128) {
        const int jn = jc + 128;
        bf16x8 nxt[4];
        if (jn < NP) {
            const u16* h2 = hbase + (size_t)(jn >> 5) * 2048;
            #pragma unroll
            for (int nt = 0; nt < 4; ++nt) nxt[nt] = *(const bf16x8*)(h2 + nt * 512);
        }
        const int jb = jc + quad * 8;
        const int tile = jc >> 5;
        const float4 a0 = *(const float4*)(sE + jb);
        const float4 a1 = *(const float4*)(sE + jb + 4);
        const float4 b0 = *(const float4*)(sE + NP + jb);
        const float4 b1 = *(const float4*)(sE + NP + jb + 4);
        const u32 w = sAdj[tile * 16 + r];
        const u32 mask8 = (w >> (quad * 8)) & 0xffu;
        float p[8];
        p[0] = fmaxf(F1 * a0.x, F2 * b0.x);
        p[1] = fmaxf(F1 * a0.y, F2 * b0.y);
        p[2] = fmaxf(F1 * a0.z, F2 * b0.z);
        p[3] = fmaxf(F1 * a0.w, F2 * b0.w);
        p[4] = fmaxf(F1 * a1.x, F2 * b1.x);
        p[5] = fmaxf(F1 * a1.y, F2 * b1.y);
        p[6] = fmaxf(F1 * a1.z, F2 * b1.z);
        p[7] = fmaxf(F1 * a1.w, F2 * b1.w);
        #pragma unroll
        for (int kk = 0; kk < 8; ++kk)
            p[kk] = ((mask8 >> kk) & 1u) ? p[kk] : 0.f;
        union { bf16x8 v; u32 w4[4]; } af;
        af.w4[0] = pk_bf16(p[0], p[1]);
        af.w4[1] = pk_bf16(p[2], p[3]);
        af.w4[2] = pk_bf16(p[4], p[5]);
        af.w4[3] = pk_bf16(p[6], p[7]);
        #pragma unroll
        for (int nt = 0; nt < 4; ++nt)
            acc[nt] = __builtin_amdgcn_mfma_f32_16x16x32_bf16(af.v, cur[nt], acc[nt], 0, 0, 0);
        accl = __builtin_amdgcn_mfma_f32_16x16x32_bf16(af.v, ones, accl, 0, 0, 0);
        #pragma unroll
        for (int nt = 0; nt < 4; ++nt) cur[nt] = nxt[nt];
    }

    // cross-wave reduction: reuse sE as red[4][64][21]
    __syncthreads();
    float* red = sE;
    #pragma unroll
    for (int nt = 0; nt < 4; ++nt)
        #pragma unroll
        for (int reg = 0; reg < 4; ++reg)
            red[(wave * 64 + lane) * 21 + nt * 4 + reg] = acc[nt][reg];
    #pragma unroll
    for (int reg = 0; reg < 4; ++reg)
        red[(wave * 64 + lane) * 21 + 16 + reg] = accl[reg];
    __syncthreads();
    if (wave != 0) return;

    #pragma unroll
    for (int nt = 0; nt < 4; ++nt)
        #pragma unroll
        for (int reg = 0; reg < 4; ++reg)
            acc[nt][reg] = red[lane * 21 + nt * 4 + reg] + red[(64 + lane) * 21 + nt * 4 + reg]
                         + red[(128 + lane) * 21 + nt * 4 + reg] + red[(192 + lane) * 21 + nt * 4 + reg];
    #pragma unroll
    for (int reg = 0; reg < 4; ++reg)
        accl[reg] = red[lane * 21 + 16 + reg] + red[(64 + lane) * 21 + 16 + reg]
                  + red[(128 + lane) * 21 + 16 + reg] + red[(192 + lane) * 21 + 16 + reg];

    const int ofp32 = sflag;
    #pragma unroll
    for (int reg = 0; reg < 4; ++reg) {
        const int ii = i0 + quad * 4 + reg;
        if (ii < NN) {
            const float lr = accl[reg];
            const float inv = (lr > 0.f) ? 1.f / lr : 0.f;   // NaN guard
            #pragma unroll
            for (int nt = 0; nt < 4; ++nt) {
                const float o = acc[nt][reg] * inv;
                const size_t idx = (size_t)ii * OC + m * 64 + nt * 16 + r;
                if (ofp32) ((float*)outv)[idx] = o;
                else       ((u16*)outv)[idx]   = f2bfu(o);
            }
        }
    }
}

// ---------------- host launch ----------------
extern "C" void kernel_launch(void* const* d_in, const int* in_sizes, int n_in,
                              void* d_out, int out_size, void* d_ws, size_t ws_size,
                              hipStream_t stream) {
    (void)in_sizes; (void)n_in; (void)out_size; (void)ws_size;
    const void* x     = d_in[0];
    const void* adj   = d_in[1];
    const void* W     = d_in[2];
    const void* a_src = d_in[3];
    const void* a_dst = d_in[4];
    const void* Wc1   = d_in[5];
    const void* bc1   = d_in[6];
    const void* Wc2   = d_in[7];
    const void* bc2   = d_in[8];

    char* ws = (char*)d_ws;
    size_t off = 0;
    auto alloc = [&](size_t bytes) -> void* {
        void* p = ws + off;
        off += (bytes + 255) & ~(size_t)255;
        return p;
    };
    u16*   xpf     = (u16*)  alloc((size_t)RP * KP * 2);         // 7.93 MB
    u16*   WTf     = (u16*)  alloc((size_t)C9 * KP * 2);         // 1.66 MB
    float* h_pre   = (float*)alloc((size_t)NN * C9 * 4);         // 6.24 MB
    float* e_srcP  = (float*)alloc((size_t)MM * NP * 4);
    float* e_dstP  = (float*)alloc((size_t)MM * NP * 4);
    u16*   HTf     = (u16*)  alloc((size_t)MM * WPR * 2048 * 2); // 2.79 MB
    u32*   adjT    = (u32*)  alloc((size_t)WPR * NP * 4);        // 0.92 MB
    float* canon   = (float*)alloc((size_t)CAN_TOT * 4);
    u32*   maxdKey = (u32*)  alloc(256);
    int*   ctr     = (int*)  alloc(256);                          // total ~19.7 MB

    hipLaunchKernelGGL(k_probe, dim3(64), dim3(256), 0, stream,
                       (const u32*)x, (const u32*)adj, ctr);
    hipLaunchKernelGGL(k_pack, dim3(PACK_TOT), dim3(256), 0, stream,
                       x, adj, W, Wc1, a_src, a_dst, bc1, bc2, Wc2,
                       xpf, WTf, adjT, canon, maxdKey, ctr);
    hipLaunchKernelGGL(k_gemm, dim3(RP / 32, 18), dim3(64), 0, stream, xpf, WTf, h_pre);
    hipLaunchKernelGGL(k_film, dim3(NP / 32, MM), dim3(256), 0, stream,
                       h_pre, canon, HTf, e_srcP, e_dstP, maxdKey);
    hipLaunchKernelGGL(k_attn, dim3((NN + 15) / 16, MM), dim3(256), 0, stream,
                       adjT, e_srcP, e_dstP, maxdKey, HTf, d_out, ctr);
}

// Round 15
// 196.280 us; speedup vs baseline: 1.0260x; 1.0260x over previous
//
#include <hip/hip_runtime.h>
#include <hip/hip_bf16.h>

// ---------------- constants ----------------
#define NN   2708      // nodes
#define INS  1433      // input features
#define MM   8         // mechanisms
#define NP   2720      // N padded to mult of 32 (j / n dimension)
#define WPR  85        // NP/32 words per adjacency row (bit-packed)
#define KP   1440      // INS padded to mult of 32
#define NKC  45        // KP/32 k-chunks
#define RP   2752      // rows padded to mult of 64 for GEMM
#define C9   576       // 9*64 columns of big GEMM (8 mechs + conditioner hidden)
#define OC   512       // M*OUTS output columns

// canon small-tensor layout (floats): a_src[512] a_dst[512] bc1[64] bc2[16] Wc2[1024]
#define CAN_ASRC 0
#define CAN_ADST 512
#define CAN_BC1  1024
#define CAN_BC2  1088
#define CAN_WC2  1104
#define CAN_TOT  2128

// fused pack kernel block ranges: [adj | x | wt | canon]
#define ADJ_WAVES (NN * 11)               // one wave per (row, 256-j chunk)
#define ADJBLK ((ADJ_WAVES + 3) / 4)      // 7447
#define XBLK   1935                        // RP*KP/2048 (8 elems/thread)
#define WTBLK  (9 * 23)                    // 207
#define PACK_TOT (ADJBLK + XBLK + WTBLK + 1)

typedef unsigned short u16;
typedef unsigned int   u32;
typedef __attribute__((ext_vector_type(8))) short bf16x8;
typedef __attribute__((ext_vector_type(4))) float f32x4;

static __device__ __forceinline__ u16 f2bfu(float f) {
    union { float f; u32 u; } v; v.f = f;
    u32 u = v.u;
    u32 r = (u + 0x7fffu + ((u >> 16) & 1u)) >> 16;   // RNE
    return (u16)r;
}
static __device__ __forceinline__ float bfu2f(u16 b) {
    union { u32 u; float f; } v; v.u = ((u32)b) << 16;
    return v.f;
}
// packed RNE f32x2 -> bf16x2 (v_cvt_pk_bf16_f32 on gfx950)
static __device__ __forceinline__ u32 pk_bf16(float a, float b) {
    union { __hip_bfloat162 h; u32 w; } p;
    p.h = __float22bfloat162_rn(make_float2(a, b));
    return p.w;
}
// ordered-uint key for float atomicMax (finite values)
static __device__ __forceinline__ u32 fkey(float f) {
    u32 u = __float_as_uint(f);
    return (u & 0x80000000u) ? ~u : (u | 0x80000000u);
}
static __device__ __forceinline__ float funkey(u32 k) {
    u32 u = (k & 0x80000000u) ? (k & 0x7fffffffu) : ~k;
    return __uint_as_float(u);
}

// ctr[0..31] = per-block x denormal counts; ctr[32..63] = per-block adj flag bits
// bits: 1=gt1, 2=bf16, 4=f32, 8=f16, 16=odd-nonzero
static __device__ __forceinline__ int aflag_decode(int b) {
    if (b & 2)  return 3;   // bf16
    if (b & 4)  return 4;   // f32
    if (b & 8)  return 5;   // f16
    if (b & 1)  return 1;   // uint8
    if (b & 16) return 0;   // int32
    return 2;               // int64
}

// ---------------- probes: no atomics, per-block result words ----------------
__global__ void k_probe(const u32* __restrict__ x_raw, const u32* __restrict__ adj_raw,
                        int* __restrict__ ctr) {
    const int b = blockIdx.x, t = threadIdx.x;
    __shared__ int sred[4];
    if (b < 32) {
        int local = 0;
        #pragma unroll
        for (int k = 0; k < 8; ++k) {
            u32 v = x_raw[b * 2048 + k * 256 + t];
            u32 lo = v & 0xffffu, hi = v >> 16;
            if ((lo & 0x7f80u) == 0u && lo != 0u) local++;   // fp32 mantissa pattern
            if ((hi & 0x7f80u) == 0u && hi != 0u) local++;
        }
        #pragma unroll
        for (int off = 32; off > 0; off >>= 1) local += __shfl_xor(local, off, 64);
        if ((t & 63) == 0) sred[t >> 6] = local;
        __syncthreads();
        if (t == 0) ctr[b] = sred[0] + sred[1] + sred[2] + sred[3];
    } else {
        int fl = 0;
        #pragma unroll
        for (int k = 0; k < 8; ++k) {
            int w = (b - 32) * 2048 + k * 256 + t;
            u32 v = adj_raw[w];
            if (v > 1u)           fl |= 1;
            if (v == 0x3f803f80u) fl |= 2;
            if (v == 0x3f800000u) fl |= 4;
            if (v == 0x3c003c00u) fl |= 8;
            if ((w & 1) && v)     fl |= 16;
        }
        #pragma unroll
        for (int off = 32; off > 0; off >>= 1) fl |= __shfl_xor(fl, off, 64);
        if ((t & 63) == 0) sred[t >> 6] = fl;
        __syncthreads();
        if (t == 0) ctr[b] = sred[0] | sred[1] | sred[2] | sred[3];
    }
}

static __device__ __forceinline__ u16 load_as_bf16(const void* p, size_t idx, int fp32) {
    if (fp32) return f2bfu(((const float*)p)[idx]);
    return ((const u16*)p)[idx];
}
static __device__ __forceinline__ float load_as_f32(const void* p, size_t idx, int fp32) {
    if (fp32) return ((const float*)p)[idx];
    return bfu2f(((const u16*)p)[idx]);
}

// ---------------- fused pack: adj-bitpack | x fragment tiles | W transpose | canon ----------------
__global__ void k_pack(const void* __restrict__ x, const void* __restrict__ adj,
                       const void* __restrict__ W, const void* __restrict__ Wc1,
                       const void* a_src, const void* a_dst, const void* bc1,
                       const void* bc2, const void* Wc2,
                       u16* __restrict__ xpf, u16* __restrict__ WTf,
                       u32* __restrict__ adjT, float* __restrict__ canon,
                       u32* __restrict__ maxdKey, const int* __restrict__ ctr) {
    __shared__ float lds[64][65];
    __shared__ int sflags[2];
    const int t = threadIdx.x;
    if (t < 64) {
        int v = ctr[t];
        int cnt  = (t < 32) ? v : 0;
        int bits = (t >= 32) ? v : 0;
        #pragma unroll
        for (int off = 32; off > 0; off >>= 1) {
            cnt  += __shfl_xor(cnt, off, 64);
            bits |= __shfl_xor(bits, off, 64);
        }
        if (t == 0) { sflags[0] = cnt; sflags[1] = bits; }
    }
    __syncthreads();
    const int fp32 = sflags[0] > 32;

    const int bid = blockIdx.x;
    if (bid < ADJBLK) {
        const int f = aflag_decode(sflags[1]);
        const int wid  = bid * 4 + (t >> 6);
        const int lane = t & 63;
        const int i = wid / 11;
        const int c256 = wid - i * 11;
        if (i >= NN) return;
        const int jb0 = c256 * 256;
        #pragma unroll
        for (int s = 0; s < 4; ++s) {
            const int jb = jb0 + s * 64;
            if (jb >= NP) break;
            const int j = jb + lane;
            int v = 0;
            if (j < NN) {
                size_t idx = (size_t)i * NN + j;
                if      (f == 0) v = ((const int*)adj)[idx] != 0;
                else if (f == 1) v = ((const unsigned char*)adj)[idx] != 0;
                else if (f == 2) v = ((const long long*)adj)[idx] != 0;
                else if (f == 4) v = ((const float*)adj)[idx] != 0.f;
                else             v = ((const u16*)adj)[idx] != 0;
            }
            unsigned long long mask = __ballot(v);
            if (lane == 0) {
                const int ww = jb >> 5;
                adjT[(size_t)ww * NP + i] = (u32)mask;
                if (ww + 1 < WPR) adjT[(size_t)(ww + 1) * NP + i] = (u32)(mask >> 32);
            }
        }
    } else if (bid < ADJBLK + XBLK) {
        const int base = (bid - ADJBLK) * 2048 + t;
        #pragma unroll
        for (int s = 0; s < 8; ++s) {
            const int e = base + s * 256;
            const int t1 = e >> 9, sub = e & 511;
            const int r = sub >> 5, kloc = sub & 31;
            const int it = t1 / NKC, kc = t1 - it * NKC;
            const int row = it * 16 + r, col = kc * 32 + kloc;
            u16 v = 0;
            if (row < NN && col < INS) v = load_as_bf16(x, (size_t)row * INS + col, fp32);
            xpf[e] = v;
        }
    } else if (bid < ADJBLK + XBLK + WTBLK) {
        const int b2 = bid - ADJBLK - XBLK;
        const int mblk = b2 / 23, ktile = b2 - mblk * 23;
        #pragma unroll
        for (int ii = 0; ii < 16; ++ii) {
            int l = t * 16 + ii;
            int k_in = l >> 6, o = l & 63;
            int k = ktile * 64 + k_in;
            float v = 0.f;
            if (k < INS) {
                if (mblk < 8) v = load_as_f32(W, ((size_t)mblk * INS + k) * 64 + o, fp32);
                else          v = load_as_f32(Wc1, (size_t)k * 64 + o, fp32);
            }
            lds[k_in][o] = v;
        }
        __syncthreads();
        #pragma unroll
        for (int ii = 0; ii < 16; ++ii) {
            int e2 = t * 16 + ii;
            int ct2 = e2 >> 10, kc2 = (e2 >> 9) & 1;
            int r = (e2 >> 5) & 15, kloc = e2 & 31;
            int kc = ktile * 2 + kc2;
            if (kc < NKC) {
                int ct = mblk * 4 + ct2;
                WTf[(((size_t)ct * NKC + kc) * 16 + r) * 32 + kloc] =
                    f2bfu(lds[kc2 * 32 + kloc][ct2 * 16 + r]);
            }
        }
    } else {
        if (t < 8) maxdKey[t] = 0u;    // identity for ordered-uint max over finite floats
        for (int e = t; e < CAN_TOT; e += 256) {
            float v;
            if      (e < CAN_ADST) v = load_as_f32(a_src, e - CAN_ASRC, fp32);
            else if (e < CAN_BC1)  v = load_as_f32(a_dst, e - CAN_ADST, fp32);
            else if (e < CAN_BC2)  v = load_as_f32(bc1,  e - CAN_BC1, fp32);
            else if (e < CAN_WC2)  v = load_as_f32(bc2,  e - CAN_BC2, fp32);
            else                   v = load_as_f32(Wc2,  e - CAN_WC2, fp32);
            canon[e] = v;
        }
    }
}

// ---------------- big GEMM: 2 row-tiles x 2 col-tiles per wave, 1548 waves ----------------
__launch_bounds__(64)
__global__ void k_gemm(const u16* __restrict__ xpf, const u16* __restrict__ WTf,
                       float* __restrict__ h_pre) {
    const int lane = threadIdx.x;
    const int r    = lane & 15;
    const int quad = lane >> 4;
    const int it0  = blockIdx.x * 2;          // two 16-row i-tiles (0..171)
    const int ct0  = blockIdx.y * 2;          // two 16-col c-tiles (0..35)

    const u16* aP0 = xpf + (size_t)it0 * NKC * 512 + r * 32 + quad * 8;
    const u16* aP1 = aP0 + (size_t)NKC * 512;
    const u16* bP0 = WTf + (size_t)ct0 * NKC * 512 + r * 32 + quad * 8;
    const u16* bP1 = bP0 + (size_t)NKC * 512;

    f32x4 acc[2][2];
    #pragma unroll
    for (int a = 0; a < 2; ++a)
        #pragma unroll
        for (int b = 0; b < 2; ++b) acc[a][b] = (f32x4){0.f, 0.f, 0.f, 0.f};

    #pragma unroll 3
    for (int kc = 0; kc < NKC; ++kc) {
        bf16x8 a0 = *(const bf16x8*)(aP0 + kc * 512);
        bf16x8 a1 = *(const bf16x8*)(aP1 + kc * 512);
        bf16x8 b0 = *(const bf16x8*)(bP0 + kc * 512);
        bf16x8 b1 = *(const bf16x8*)(bP1 + kc * 512);
        acc[0][0] = __builtin_amdgcn_mfma_f32_16x16x32_bf16(a0, b0, acc[0][0], 0, 0, 0);
        acc[0][1] = __builtin_amdgcn_mfma_f32_16x16x32_bf16(a0, b1, acc[0][1], 0, 0, 0);
        acc[1][0] = __builtin_amdgcn_mfma_f32_16x16x32_bf16(a1, b0, acc[1][0], 0, 0, 0);
        acc[1][1] = __builtin_amdgcn_mfma_f32_16x16x32_bf16(a1, b1, acc[1][1], 0, 0, 0);
    }

    #pragma unroll
    for (int a = 0; a < 2; ++a) {
        #pragma unroll
        for (int reg = 0; reg < 4; ++reg) {
            const int ii = (it0 + a) * 16 + quad * 4 + reg;
            if (ii < NN) {
                float* orow = h_pre + (size_t)ii * C9 + ct0 * 16;
                orow[ 0 + r] = acc[a][0][reg];
                orow[16 + r] = acc[a][1][reg];
            }
        }
    }
}

// ---------------- FiLM + inline conditioner + scores + HT tiles + maxd atomicMax ----------------
__launch_bounds__(256)
__global__ void k_film(const float* __restrict__ h_pre, const float* __restrict__ canon,
                       u16* __restrict__ HTf, float* __restrict__ e_srcP,
                       float* __restrict__ e_dstP, u32* __restrict__ maxdKey) {
    const int m  = blockIdx.y;
    const int n0 = blockIdx.x * 32;
    const int t  = threadIdx.x, wave = t >> 6, o = t & 63;
    __shared__ float hbuf[32][66];   // fp32; +2 pad
    __shared__ float smx[4];

    const float wg = canon[CAN_WC2 + o * 16 + m];
    const float wb = canon[CAN_WC2 + o * 16 + m + 8];
    const float as = canon[CAN_ASRC + m * 64 + o];
    const float ad = canon[CAN_ADST + m * 64 + o];
    const float b1 = canon[CAN_BC1 + o];
    const float g0 = canon[CAN_BC2 + m], b0 = canon[CAN_BC2 + m + 8];

    float mxd = -3.0e38f;
    #pragma unroll
    for (int it = 0; it < 8; ++it) {
        const int nl = wave * 8 + it, n = n0 + nl;
        const bool valid = n < NN;
        float hv = 0.f;
        if (valid) hv = h_pre[(size_t)n * C9 + 512 + o] + b1;   // coalesced 256 B row
        hv = hv > 0.f ? hv : 0.f;
        float pg = hv * wg, pb = hv * wb;
        #pragma unroll
        for (int off = 32; off > 0; off >>= 1) {
            pg += __shfl_xor(pg, off, 64);
            pb += __shfl_xor(pb, off, 64);
        }
        const float g = pg + g0, bb = pb + b0;
        float h = 0.f;
        if (valid) h = g * h_pre[(size_t)n * C9 + m * 64 + o] + bb;  // coalesced
        float ps = h * as, pd = h * ad;
        #pragma unroll
        for (int off = 32; off > 0; off >>= 1) {
            ps += __shfl_xor(ps, off, 64);
            pd += __shfl_xor(pd, off, 64);
        }
        if (o == 0) { e_srcP[m * NP + n] = ps; e_dstP[m * NP + n] = pd; }
        mxd = fmaxf(mxd, pd);                 // pd identical on all lanes after butterfly
        hbuf[nl][o] = h;
    }
    if (o == 0) smx[wave] = mxd;
    __syncthreads();
    if (t == 0) {
        const float bm = fmaxf(fmaxf(smx[0], smx[1]), fmaxf(smx[2], smx[3]));
        atomicMax(&maxdKey[m], fkey(bm));
    }
    // write one fragment-major HT tile (o-major, 32-j inner), fully coalesced
    u32* ht32 = (u32*)(HTf + ((size_t)m * WPR + (n0 >> 5)) * 2048);
    #pragma unroll
    for (int rep = 0; rep < 4; ++rep) {
        const int idx = rep * 256 + t;
        const int oo = idx >> 4, jp = idx & 15;
        ht32[idx] = pk_bf16(hbuf[2 * jp][oo], hbuf[2 * jp + 1][oo]);
    }
}

// ---------------- attention + PV: E/F computed in staging, packed cvt, ones-MFMA l ----------------
__launch_bounds__(256)
__global__ void k_attn(const u32* __restrict__ adjT, const float* __restrict__ e_srcP,
                       const float* __restrict__ e_dstP, const u32* __restrict__ maxdKey,
                       const u16* __restrict__ HTf, void* __restrict__ outv,
                       const int* __restrict__ ctr) {
    const int m = blockIdx.y, i0 = blockIdx.x * 16;
    const int t = threadIdx.x;
    const int wave = t >> 6, lane = t & 63;
    const int r = lane & 15, quad = lane >> 4;
    const int i = min(i0 + r, NN - 1);

    __shared__ float sE[2 * NP];      // E1 | E2; reused as reduction buffer after loop
    __shared__ u32 sAdj[WPR * 16];    // [tile][r]
    __shared__ int sflag;

    const float maxd = funkey(maxdKey[m]);
    if (t == 0) {
        int s = 0;
        #pragma unroll
        for (int k = 0; k < 32; ++k) s += ctr[k];
        sflag = s > 32;
    }
    for (int idx = t; idx < NP; idx += 256) {
        const float d = e_dstP[m * NP + idx] - maxd;
        sE[idx]      = __expf(d);
        sE[NP + idx] = __expf(0.2f * d);
    }
    for (int w = t; w < WPR * 16; w += 256) {
        const int tile = w >> 4, rr = w & 15;
        sAdj[w] = adjT[(size_t)tile * NP + min(i0 + rr, NN - 1)];
    }
    __syncthreads();

    const float v0 = e_srcP[m * NP + i] + maxd;
    const float rmax = v0 > 0.f ? v0 : 0.2f * v0;
    const float F1 = __expf(v0 - rmax);
    const float F2 = __expf(0.2f * v0 - rmax);
    const u16* hbase = HTf + (size_t)m * WPR * 2048 + r * 32 + quad * 8;

    f32x4 acc[4], accl;
    #pragma unroll
    for (int nt = 0; nt < 4; ++nt) acc[nt] = (f32x4){0.f, 0.f, 0.f, 0.f};
    accl = (f32x4){0.f, 0.f, 0.f, 0.f};

    bf16x8 ones;
    #pragma unroll
    for (int kk = 0; kk < 8; ++kk) ones[kk] = (short)0x3f80;

    // waves round-robin over j-chunks; partials additive (shared rmax bound)
    #pragma unroll 2
    for (int jc = wave * 32; jc < NP; jc += 128) {
        const int jb = jc + quad * 8;
        const int tile = jc >> 5;
        const float4 a0 = *(const float4*)(sE + jb);
        const float4 a1 = *(const float4*)(sE + jb + 4);
        const float4 b0 = *(const float4*)(sE + NP + jb);
        const float4 b1 = *(const float4*)(sE + NP + jb + 4);
        const u32 w = sAdj[tile * 16 + r];
        const u32 mask8 = (w >> (quad * 8)) & 0xffu;
        float p[8];
        p[0] = fmaxf(F1 * a0.x, F2 * b0.x);
        p[1] = fmaxf(F1 * a0.y, F2 * b0.y);
        p[2] = fmaxf(F1 * a0.z, F2 * b0.z);
        p[3] = fmaxf(F1 * a0.w, F2 * b0.w);
        p[4] = fmaxf(F1 * a1.x, F2 * b1.x);
        p[5] = fmaxf(F1 * a1.y, F2 * b1.y);
        p[6] = fmaxf(F1 * a1.z, F2 * b1.z);
        p[7] = fmaxf(F1 * a1.w, F2 * b1.w);
        #pragma unroll
        for (int kk = 0; kk < 8; ++kk)
            p[kk] = ((mask8 >> kk) & 1u) ? p[kk] : 0.f;
        union { bf16x8 v; u32 w4[4]; } af;
        af.w4[0] = pk_bf16(p[0], p[1]);
        af.w4[1] = pk_bf16(p[2], p[3]);
        af.w4[2] = pk_bf16(p[4], p[5]);
        af.w4[3] = pk_bf16(p[6], p[7]);
        const u16* ht = hbase + (size_t)tile * 2048;
        #pragma unroll
        for (int nt = 0; nt < 4; ++nt) {
            bf16x8 bf = *(const bf16x8*)(ht + nt * 512);   // 1 KB/wave, fully coalesced
            acc[nt] = __builtin_amdgcn_mfma_f32_16x16x32_bf16(af.v, bf, acc[nt], 0, 0, 0);
        }
        accl = __builtin_amdgcn_mfma_f32_16x16x32_bf16(af.v, ones, accl, 0, 0, 0);
    }

    // cross-wave reduction: reuse sE as red[4][64][21]
    __syncthreads();
    float* red = sE;
    #pragma unroll
    for (int nt = 0; nt < 4; ++nt)
        #pragma unroll
        for (int reg = 0; reg < 4; ++reg)
            red[(wave * 64 + lane) * 21 + nt * 4 + reg] = acc[nt][reg];
    #pragma unroll
    for (int reg = 0; reg < 4; ++reg)
        red[(wave * 64 + lane) * 21 + 16 + reg] = accl[reg];
    __syncthreads();
    if (wave != 0) return;

    #pragma unroll
    for (int nt = 0; nt < 4; ++nt)
        #pragma unroll
        for (int reg = 0; reg < 4; ++reg)
            acc[nt][reg] = red[lane * 21 + nt * 4 + reg] + red[(64 + lane) * 21 + nt * 4 + reg]
                         + red[(128 + lane) * 21 + nt * 4 + reg] + red[(192 + lane) * 21 + nt * 4 + reg];
    #pragma unroll
    for (int reg = 0; reg < 4; ++reg)
        accl[reg] = red[lane * 21 + 16 + reg] + red[(64 + lane) * 21 + 16 + reg]
                  + red[(128 + lane) * 21 + 16 + reg] + red[(192 + lane) * 21 + 16 + reg];

    const int ofp32 = sflag;
    #pragma unroll
    for (int reg = 0; reg < 4; ++reg) {
        const int ii = i0 + quad * 4 + reg;
        if (ii < NN) {
            const float lr = accl[reg];
            const float inv = (lr > 0.f) ? 1.f / lr : 0.f;   // NaN guard
            #pragma unroll
            for (int nt = 0; nt < 4; ++nt) {
                const float o = acc[nt][reg] * inv;
                const size_t idx = (size_t)ii * OC + m * 64 + nt * 16 + r;
                if (ofp32) ((float*)outv)[idx] = o;
                else       ((u16*)outv)[idx]   = f2bfu(o);
            }
        }
    }
}

// ---------------- host launch ----------------
extern "C" void kernel_launch(void* const* d_in, const int* in_sizes, int n_in,
                              void* d_out, int out_size, void* d_ws, size_t ws_size,
                              hipStream_t stream) {
    (void)in_sizes; (void)n_in; (void)out_size; (void)ws_size;
    const void* x     = d_in[0];
    const void* adj   = d_in[1];
    const void* W     = d_in[2];
    const void* a_src = d_in[3];
    const void* a_dst = d_in[4];
    const void* Wc1   = d_in[5];
    const void* bc1   = d_in[6];
    const void* Wc2   = d_in[7];
    const void* bc2   = d_in[8];

    char* ws = (char*)d_ws;
    size_t off = 0;
    auto alloc = [&](size_t bytes) -> void* {
        void* p = ws + off;
        off += (bytes + 255) & ~(size_t)255;
        return p;
    };
    u16*   xpf     = (u16*)  alloc((size_t)RP * KP * 2);         // 7.93 MB
    u16*   WTf     = (u16*)  alloc((size_t)C9 * KP * 2);         // 1.66 MB
    float* h_pre   = (float*)alloc((size_t)NN * C9 * 4);         // 6.24 MB
    float* e_srcP  = (float*)alloc((size_t)MM * NP * 4);
    float* e_dstP  = (float*)alloc((size_t)MM * NP * 4);
    u16*   HTf     = (u16*)  alloc((size_t)MM * WPR * 2048 * 2); // 2.79 MB
    u32*   adjT    = (u32*)  alloc((size_t)WPR * NP * 4);        // 0.92 MB
    float* canon   = (float*)alloc((size_t)CAN_TOT * 4);
    u32*   maxdKey = (u32*)  alloc(256);
    int*   ctr     = (int*)  alloc(256);                          // total ~19.7 MB

    hipLaunchKernelGGL(k_probe, dim3(64), dim3(256), 0, stream,
                       (const u32*)x, (const u32*)adj, ctr);
    hipLaunchKernelGGL(k_pack, dim3(PACK_TOT), dim3(256), 0, stream,
                       x, adj, W, Wc1, a_src, a_dst, bc1, bc2, Wc2,
                       xpf, WTf, adjT, canon, maxdKey, ctr);
    hipLaunchKernelGGL(k_gemm, dim3(RP / 32, 18), dim3(64), 0, stream, xpf, WTf, h_pre);
    hipLaunchKernelGGL(k_film, dim3(NP / 32, MM), dim3(256), 0, stream,
                       h_pre, canon, HTf, e_srcP, e_dstP, maxdKey);
    hipLaunchKernelGGL(k_attn, dim3((NN + 15) / 16, MM), dim3(256), 0, stream,
                       adjT, e_srcP, e_dstP, maxdKey, HTf, d_out, ctr);
}